// Round 1
// baseline (32.783 us; speedup 1.0000x reference)
//
#include <hip/hip_runtime.h>
#include <hip/hip_bf16.h>
#include <stdint.h>

// MultiDense: out[b,s,:] = values[b,s,:] @ W[lookups[b]] + bias[lookups[b]]
// B=16384, S=4, IN=OUT=128, 64 experts.
//
// Strategy: one kernel. Grid = 64 experts x 8 chunks. Block (e,c) scans
// lookups[c*2048 .. (c+1)*2048) for ==e (compact into LDS list), stages
// W[e]^T into LDS as bf16 (XOR-swizzled rows to avoid 16-way bank conflicts
// on ds_read_b128 B-fragments), then per-wave 32-row x 128-col MFMA tiles
// (mfma_f32_16x16x32_bf16), A-fragments gathered directly from global fp32
// values (each row read exactly once, 64B-granular).

#define NDIMS   64
#define IN_DIM  128
#define OUT_DIM 128
#define BATCH   16384
#define SEQ     4
#define NC      8                  // chunks per expert
#define CHUNK   (BATCH / NC)       // 2048
#define THREADS 256
#define NWAVE   4

using bf16x8 = __attribute__((ext_vector_type(8))) __bf16;
using f32x4  = __attribute__((ext_vector_type(4))) float;

static __device__ inline uint16_t bf16bits(float f) {
    __bf16 h = (__bf16)f;                   // RNE convert
    return __builtin_bit_cast(uint16_t, h);
}

static __device__ inline bf16x8 cvt8(f32x4 v0, f32x4 v1) {
    bf16x8 r;
    r[0] = (__bf16)v0[0]; r[1] = (__bf16)v0[1];
    r[2] = (__bf16)v0[2]; r[3] = (__bf16)v0[3];
    r[4] = (__bf16)v1[0]; r[5] = (__bf16)v1[1];
    r[6] = (__bf16)v1[2]; r[7] = (__bf16)v1[3];
    return r;
}

__global__ __launch_bounds__(THREADS)
void multidense_kernel(const float* __restrict__ values,
                       const float* __restrict__ W,
                       const float* __restrict__ bias,
                       const int*   __restrict__ lookups,
                       float*       __restrict__ out)
{
    // LDS: W[e]^T as bf16, swizzled: byte (n*256 + x) holds Wt[n][(x ^ ((n&7)<<4))/2]
    __shared__ __align__(16) unsigned char w_lds[OUT_DIM * IN_DIM * 2];  // 32 KiB
    __shared__ int list[CHUNK];                                          // 8 KiB (worst case)
    __shared__ int nm_sh;

    const int tid = threadIdx.x;
    const int e   = blockIdx.x >> 3;        // expert (8 consecutive blocks share e -> L2 reuse)
    const int c   = blockIdx.x & (NC - 1);  // chunk

    if (tid == 0) nm_sh = 0;
    __syncthreads();

    // ---- Stage W[e]^T -> LDS bf16, transposed + swizzled ----
    // thread: o = tid&127 (coalesced global reads), pairs of i
    {
        const float* We = W + (size_t)e * IN_DIM * OUT_DIM;
        const int o   = tid & 127;
        const int ih  = tid >> 7;            // 0..1
        const int swz = (o & 7) << 4;
        unsigned char* wrow = &w_lds[o * 256];
        #pragma unroll 4
        for (int ii = 0; ii < 32; ++ii) {
            int i0 = ih * 2 + ii * 4;        // even i in [0,128)
            float f0 = We[(i0    ) * OUT_DIM + o];
            float f1 = We[(i0 + 1) * OUT_DIM + o];
            uint32_t pk = (uint32_t)bf16bits(f0) | ((uint32_t)bf16bits(f1) << 16);
            *(uint32_t*)(wrow + ((i0 * 2) ^ swz)) = pk;
        }
    }

    // ---- Scan this chunk of lookups for expert e ----
    {
        const int cbase = c * CHUNK;
        for (int t = tid; t < CHUNK; t += THREADS) {
            if (lookups[cbase + t] == e) {
                int p = atomicAdd(&nm_sh, 1);
                list[p] = cbase + t;         // sample index b
            }
        }
    }
    __syncthreads();

    const int nm = nm_sh;
    if (nm == 0) return;

    const int lane = tid & 63;
    const int wid  = tid >> 6;
    const int l15  = lane & 15;
    const int l4   = lane >> 4;              // 0..3
    const int swzB = (l15 & 7) << 4;         // B-fragment row swizzle (n&7 == l15&7)

    // bias per lane, one per n-fragment
    float bias_c[8];
    #pragma unroll
    for (int nf = 0; nf < 8; ++nf) bias_c[nf] = bias[e * OUT_DIM + nf * 16 + l15];

    // ---- Main loop: each wave takes groups of 8 samples (32 GEMM rows) ----
    for (int grp = wid; grp * 8 < nm; grp += NWAVE) {
        const int sbase = grp * 8;

        // A row pointers (fragment layout: row = l15, k = ks*32 + l4*8 + j)
        const float* pA[2];
        #pragma unroll
        for (int mf = 0; mf < 2; ++mf) {
            int row  = mf * 16 + l15;                 // row in 32-row group
            int pos  = sbase + (row >> 2);
            int posc = pos < nm ? pos : nm - 1;       // clamp tail (stores masked below)
            int b    = list[posc];
            pA[mf] = values + (size_t)(b * SEQ + (row & 3)) * IN_DIM + l4 * 8;
        }

        f32x4 acc[2][8];
        #pragma unroll
        for (int mf = 0; mf < 2; ++mf)
            #pragma unroll
            for (int nf = 0; nf < 8; ++nf) {
                f32x4 a; a[0] = bias_c[nf]; a[1] = bias_c[nf]; a[2] = bias_c[nf]; a[3] = bias_c[nf];
                acc[mf][nf] = a;
            }

        #pragma unroll
        for (int ks = 0; ks < 4; ++ks) {
            bf16x8 afr[2];
            #pragma unroll
            for (int mf = 0; mf < 2; ++mf) {
                f32x4 v0 = *(const f32x4*)(pA[mf] + ks * 32);
                f32x4 v1 = *(const f32x4*)(pA[mf] + ks * 32 + 4);
                afr[mf] = cvt8(v0, v1);
            }
            const int koff = (ks * 64 + l4 * 16) ^ swzB;
            #pragma unroll
            for (int nf = 0; nf < 8; ++nf) {
                const bf16x8 bfr = *(const bf16x8*)(&w_lds[(nf * 16 + l15) * 256 + koff]);
                acc[0][nf] = __builtin_amdgcn_mfma_f32_16x16x32_bf16(afr[0], bfr, acc[0][nf], 0, 0, 0);
                acc[1][nf] = __builtin_amdgcn_mfma_f32_16x16x32_bf16(afr[1], bfr, acc[1][nf], 0, 0, 0);
            }
        }

        // ---- Store: D layout col = l15, row = l4*4 + r (per 16-row fragment) ----
        #pragma unroll
        for (int mf = 0; mf < 2; ++mf) {
            #pragma unroll
            for (int r = 0; r < 4; ++r) {
                int row = mf * 16 + l4 * 4 + r;
                int pos = sbase + (row >> 2);
                if (pos < nm) {
                    int b = list[pos];
                    float* po = out + (size_t)(b * SEQ + (row & 3)) * OUT_DIM + l15;
                    #pragma unroll
                    for (int nf = 0; nf < 8; ++nf) po[nf * 16] = acc[mf][nf][r];
                }
            }
        }
    }
}

extern "C" void kernel_launch(void* const* d_in, const int* in_sizes, int n_in,
                              void* d_out, int out_size, void* d_ws, size_t ws_size,
                              hipStream_t stream) {
    const float* values  = (const float*)d_in[0];
    const float* W       = (const float*)d_in[1];
    const float* bias    = (const float*)d_in[2];
    const int*   lookups = (const int*)d_in[3];
    float* out = (float*)d_out;

    hipLaunchKernelGGL(multidense_kernel, dim3(NDIMS * NC), dim3(THREADS), 0, stream,
                       values, W, bias, lookups, out);
}